// Round 1
// baseline (1131.721 us; speedup 1.0000x reference)
//
#include <hip/hip_runtime.h>

#define N_TOK 32768
#define D 256
#define DFF 1024
#define NE 8

using f32x4   = __attribute__((ext_vector_type(4))) float;
using short4v = __attribute__((ext_vector_type(4))) short;

// fp32 -> bf16 round-to-nearest-even
__device__ __forceinline__ short f2bf(float f) {
    union { float f; unsigned u; } v; v.f = f;
    unsigned r = v.u + 0x7FFFu + ((v.u >> 16) & 1u);
    return (short)(r >> 16);
}

// ---------------------------------------------------------------------------
// Pre-pass: per-expert transpose + fp32->bf16 of a weight matrix.
// src: [E][R][C] fp32   ->  dst: [E][C][R] bf16
// 64x64 tiles, 256 threads.
// ---------------------------------------------------------------------------
__global__ __launch_bounds__(256) void transpose_to_bf16(
    const float* __restrict__ src, short* __restrict__ dst, int R, int C) {
    __shared__ short tile[64][65];
    const int tid = threadIdx.x;
    const int ncb = C >> 6;
    const int tilesPer = (R >> 6) * ncb;
    int b = blockIdx.x;
    int e = b / tilesPer;
    int t = b - e * tilesPer;
    int tr = t / ncb, tc = t - tr * ncb;

    const float* s = src + (size_t)e * R * C + (size_t)(tr * 64) * C + tc * 64;
#pragma unroll
    for (int p = 0; p < 4; ++p) {
        int r = p * 16 + (tid >> 4);
        int c = (tid & 15) * 4;
        float4 v = *(const float4*)(s + (size_t)r * C + c);
        tile[r][c + 0] = f2bf(v.x);
        tile[r][c + 1] = f2bf(v.y);
        tile[r][c + 2] = f2bf(v.z);
        tile[r][c + 3] = f2bf(v.w);
    }
    __syncthreads();
    short* dp = dst + (size_t)e * R * C + (size_t)(tc * 64) * R + tr * 64;
#pragma unroll
    for (int p = 0; p < 4; ++p) {
        int orow = p * 16 + (tid >> 4);
        int oc = (tid & 15) * 4;
        short4v v;
        v[0] = tile[oc + 0][orow];
        v[1] = tile[oc + 1][orow];
        v[2] = tile[oc + 2][orow];
        v[3] = tile[oc + 3][orow];
        *(short4v*)(dp + (size_t)orow * R + oc) = v;
    }
}

// ---------------------------------------------------------------------------
// Gating: one wave per token. fp64-accumulated logits (selection robustness),
// softmax in fp64, top-2 with lowest-index tie-break (matches lax.top_k),
// atomic binning into per-expert token lists.
// ---------------------------------------------------------------------------
__global__ __launch_bounds__(256) void gate_topk_bin(
    const float* __restrict__ x, const float* __restrict__ gw,
    const float* __restrict__ gb,
    int* __restrict__ cnt, int* __restrict__ bidx, float* __restrict__ bp) {
    const int lane = threadIdx.x & 63;
    const int wid  = threadIdx.x >> 6;
    const int t = blockIdx.x * 4 + wid;

    float4 xv = *(const float4*)(x + (size_t)t * D + lane * 4);
    const float* g0 = gw + lane * 32;  // gw[(4*lane + j)*8 + e]
    float xa[4] = {xv.x, xv.y, xv.z, xv.w};

    double acc[NE];
#pragma unroll
    for (int e = 0; e < NE; ++e) acc[e] = 0.0;
#pragma unroll
    for (int j = 0; j < 4; ++j)
#pragma unroll
        for (int e = 0; e < NE; ++e)
            acc[e] += (double)xa[j] * (double)g0[j * 8 + e];

#pragma unroll
    for (int e = 0; e < NE; ++e) {
        double v = acc[e];
#pragma unroll
        for (int s = 1; s < 64; s <<= 1) v += __shfl_xor(v, s, 64);
        acc[e] = v;
    }

    if (lane == 0) {
        double l[NE];
#pragma unroll
        for (int e = 0; e < NE; ++e) l[e] = acc[e] + (double)gb[e];
        int e1 = 0;
#pragma unroll
        for (int e = 1; e < NE; ++e) if (l[e] > l[e1]) e1 = e;
        int e2 = (e1 == 0) ? 1 : 0;
#pragma unroll
        for (int e = 0; e < NE; ++e) if (e != e1 && l[e] > l[e2]) e2 = e;

        double s = 0.0;
#pragma unroll
        for (int e = 0; e < NE; ++e) s += exp(l[e] - l[e1]);
        float p1 = (float)(1.0 / s);
        float p2 = (float)(exp(l[e2] - l[e1]) / s);

        int pos1 = atomicAdd(&cnt[e1], 1);
        bidx[e1 * N_TOK + pos1] = t;
        bp[e1 * N_TOK + pos1] = p1;
        int pos2 = atomicAdd(&cnt[e2], 1);
        bidx[e2 * N_TOK + pos2] = t;
        bp[e2 * N_TOK + pos2] = p2;
    }
}

// ---------------------------------------------------------------------------
// Expert FFN: fused relu(x@w1+b1)@w2+b2, 64-token x 256-out tile per block,
// DFF chunked by 32 (h stays in LDS). 4 waves; wave w owns token rows
// [16w,16w+16). MFMA 16x16x16 bf16 (_1k): A row=l&15,k=4*(l>>4)+j;
// D col=l&15,row=4*(l>>4)+reg.  blockIdx&7 = expert -> per-XCD L2 affinity.
// ---------------------------------------------------------------------------
__global__ __launch_bounds__(256) void expert_ffn(
    const float* __restrict__ x,
    const short* __restrict__ w1t_g,  // [E][DFF][D] bf16
    const short* __restrict__ w2t_g,  // [E][D][DFF] bf16
    const float* __restrict__ b1, const float* __restrict__ b2,
    const int* __restrict__ cnt, const int* __restrict__ bidx,
    const float* __restrict__ bp, float* __restrict__ out) {
    const int e    = blockIdx.x & 7;
    const int tile = blockIdx.x >> 3;
    const int n_e  = cnt[e];
    const int row0 = tile * 64;
    if (row0 >= n_e) return;

    __shared__ short xs[64][264];   // x tile, bf16   (33 KB)
    __shared__ short w1s[32][264];  // [f_local][d]   (17 KB)
    __shared__ short w2s[256][44];  // [d][f_local]   (22 KB)
    __shared__ short hs[64][44];    // [token][f_loc] ( 6 KB)
    __shared__ int   tok_s[64];
    __shared__ float p_s[64];

    const int tid  = threadIdx.x;
    const int lane = tid & 63, wid = tid >> 6;
    const int r16  = lane & 15, g = lane >> 4;

    if (tid < 64) {
        int r = row0 + tid;
        if (r < n_e) { tok_s[tid] = bidx[e * N_TOK + r]; p_s[tid] = bp[e * N_TOK + r]; }
        else         { tok_s[tid] = -1;                  p_s[tid] = 0.f; }
    }
    __syncthreads();

    // gather x rows -> xs (bf16); invalid rows zero-filled
#pragma unroll
    for (int rr = 0; rr < 64; rr += 4) {
        int r = rr + (tid >> 6);
        int c = (tid & 63) * 4;
        int tk = tok_s[r];
        float4 v = make_float4(0.f, 0.f, 0.f, 0.f);
        if (tk >= 0) v = *(const float4*)(x + (size_t)tk * D + c);
        xs[r][c + 0] = f2bf(v.x);
        xs[r][c + 1] = f2bf(v.y);
        xs[r][c + 2] = f2bf(v.z);
        xs[r][c + 3] = f2bf(v.w);
    }

    f32x4 acc[16];
#pragma unroll
    for (int i = 0; i < 16; ++i) acc[i] = (f32x4){0.f, 0.f, 0.f, 0.f};

    const size_t w1base = (size_t)e * DFF * D;
    const size_t w2base = (size_t)e * D * DFF;
    const int arow = wid * 16 + r16;

    for (int fc = 0; fc < DFF; fc += 32) {
        // stage w1 chunk: [fc..fc+32)[0..256) -> w1s[fl][d]  (contiguous copies)
        {
            int fl = tid >> 3;
            int c8 = (tid & 7) * 32;
            const short* sp = w1t_g + w1base + (size_t)(fc + fl) * D + c8;
            short* dp = &w1s[fl][c8];
#pragma unroll
            for (int i = 0; i < 4; ++i)
                *(int4*)(dp + i * 8) = *(const int4*)(sp + i * 8);
        }
        // stage w2 chunk: [d][fc..fc+32) -> w2s[d][fl]
        {
            const short* sp = w2t_g + w2base + (size_t)tid * DFF + fc;
            short* dp = &w2s[tid][0];
#pragma unroll
            for (int i = 0; i < 8; ++i)
                *(short4v*)(dp + i * 4) = *(const short4v*)(sp + i * 4);
        }
        __syncthreads();

        // GEMM1: h[64][32] = xs[64][256] @ w1chunk[256][32]
        f32x4 hacc[2] = {{0.f,0.f,0.f,0.f},{0.f,0.f,0.f,0.f}};
#pragma unroll
        for (int ks = 0; ks < 16; ++ks) {
            int k0 = ks * 16 + g * 4;
            short4v a = *(const short4v*)&xs[arow][k0];
#pragma unroll
            for (int c = 0; c < 2; ++c) {
                short4v b = *(const short4v*)&w1s[c * 16 + r16][k0];
                hacc[c] = __builtin_amdgcn_mfma_f32_16x16x16bf16_1k(a, b, hacc[c], 0, 0, 0);
            }
        }
        // bias + relu -> hs (bf16)
#pragma unroll
        for (int c = 0; c < 2; ++c) {
            float b1v = b1[e * DFF + fc + c * 16 + r16];
#pragma unroll
            for (int j = 0; j < 4; ++j) {
                float hv = hacc[c][j] + b1v;
                hv = fmaxf(hv, 0.f);
                hs[wid * 16 + g * 4 + j][c * 16 + r16] = f2bf(hv);
            }
        }
        __syncthreads();

        // GEMM2: out[64][256] += hs[64][32] @ w2chunk[32][256]
#pragma unroll
        for (int ks = 0; ks < 2; ++ks) {
            int k0 = ks * 16 + g * 4;
            short4v a = *(const short4v*)&hs[arow][k0];
#pragma unroll
            for (int nc = 0; nc < 16; ++nc) {
                short4v b = *(const short4v*)&w2s[nc * 16 + r16][k0];
                acc[nc] = __builtin_amdgcn_mfma_f32_16x16x16bf16_1k(a, b, acc[nc], 0, 0, 0);
            }
        }
        __syncthreads();  // protect w1s/w2s/hs before next chunk's staging
    }

    // epilogue: out[tok] += p * (acc + b2)   (exactly 2 atomic adds/element
    // from a zeroed buffer -> bitwise deterministic)
#pragma unroll
    for (int j = 0; j < 4; ++j) {
        int r = wid * 16 + g * 4 + j;
        int tk = tok_s[r];
        if (tk < 0) continue;
        float pv = p_s[r];
        float* orow = out + (size_t)tk * D;
#pragma unroll
        for (int nc = 0; nc < 16; ++nc) {
            int dcol = nc * 16 + r16;
            float v = (acc[nc][j] + b2[e * D + dcol]) * pv;
            atomicAdd(orow + dcol, v);
        }
    }
}

// ---------------------------------------------------------------------------
extern "C" void kernel_launch(void* const* d_in, const int* in_sizes, int n_in,
                              void* d_out, int out_size, void* d_ws, size_t ws_size,
                              hipStream_t stream) {
    const float* x  = (const float*)d_in[0];
    const float* gw = (const float*)d_in[1];
    const float* gb = (const float*)d_in[2];
    const float* w1 = (const float*)d_in[3];
    const float* b1 = (const float*)d_in[4];
    const float* w2 = (const float*)d_in[5];
    const float* b2 = (const float*)d_in[6];
    float* out = (float*)d_out;

    // ws layout: cnt[8] (pad 256B) | bidx 8*N int (1MB) | bp 8*N f32 (1MB)
    //          | w1t bf16 [E][DFF][D] (4MB) | w2t bf16 [E][D][DFF] (4MB)
    char* ws = (char*)d_ws;
    int*   cnt   = (int*)ws;
    int*   bidx  = (int*)(ws + 256);
    float* bp    = (float*)(ws + 256 + (size_t)NE * N_TOK * 4);
    short* w1t_g = (short*)(ws + 256 + (size_t)NE * N_TOK * 8);
    short* w2t_g = w1t_g + (size_t)NE * D * DFF;

    hipMemsetAsync(cnt, 0, 256, stream);
    hipMemsetAsync(d_out, 0, (size_t)out_size * sizeof(float), stream);

    transpose_to_bf16<<<NE * (D / 64) * (DFF / 64), 256, 0, stream>>>(w1, w1t_g, D, DFF);
    transpose_to_bf16<<<NE * (DFF / 64) * (D / 64), 256, 0, stream>>>(w2, w2t_g, DFF, D);
    gate_topk_bin<<<N_TOK / 4, 256, 0, stream>>>(x, gw, gb, cnt, bidx, bp);
    expert_ffn<<<NE * (N_TOK / 64), 256, 0, stream>>>(x, w1t_g, w2t_g, b1, b2,
                                                      cnt, bidx, bp, out);
}

// Round 2
// 537.390 us; speedup vs baseline: 2.1060x; 2.1060x over previous
//
#include <hip/hip_runtime.h>

#define N_TOK 32768
#define D 256
#define DFF 1024
#define NE 8

using f32x4   = __attribute__((ext_vector_type(4))) float;
using short4v = __attribute__((ext_vector_type(4))) short;

// fp32 -> bf16 round-to-nearest-even
__device__ __forceinline__ short f2bf(float f) {
    union { float f; unsigned u; } v; v.f = f;
    unsigned r = v.u + 0x7FFFu + ((v.u >> 16) & 1u);
    return (short)(r >> 16);
}

// ---------------------------------------------------------------------------
// Pre-pass: per-expert transpose + fp32->bf16 of a weight matrix.
// src: [E][R][C] fp32   ->  dst: [E][C][R] bf16
// 64x64 tiles, 256 threads.
// ---------------------------------------------------------------------------
__global__ __launch_bounds__(256) void transpose_to_bf16(
    const float* __restrict__ src, short* __restrict__ dst, int R, int C) {
    __shared__ short tile[64][65];
    const int tid = threadIdx.x;
    const int ncb = C >> 6;
    const int tilesPer = (R >> 6) * ncb;
    int b = blockIdx.x;
    int e = b / tilesPer;
    int t = b - e * tilesPer;
    int tr = t / ncb, tc = t - tr * ncb;

    const float* s = src + (size_t)e * R * C + (size_t)(tr * 64) * C + tc * 64;
#pragma unroll
    for (int p = 0; p < 4; ++p) {
        int r = p * 16 + (tid >> 4);
        int c = (tid & 15) * 4;
        float4 v = *(const float4*)(s + (size_t)r * C + c);
        tile[r][c + 0] = f2bf(v.x);
        tile[r][c + 1] = f2bf(v.y);
        tile[r][c + 2] = f2bf(v.z);
        tile[r][c + 3] = f2bf(v.w);
    }
    __syncthreads();
    short* dp = dst + (size_t)e * R * C + (size_t)(tc * 64) * R + tr * 64;
#pragma unroll
    for (int p = 0; p < 4; ++p) {
        int orow = p * 16 + (tid >> 4);
        int oc = (tid & 15) * 4;
        short4v v;
        v[0] = tile[oc + 0][orow];
        v[1] = tile[oc + 1][orow];
        v[2] = tile[oc + 2][orow];
        v[3] = tile[oc + 3][orow];
        *(short4v*)(dp + (size_t)orow * R + oc) = v;
    }
}

// ---------------------------------------------------------------------------
// Gating v2: one block = 256 tokens (wave w owns tokens [64w, 64w+64)).
// Per-token fp64 logits via butterfly reduce (matches np selection), top-2,
// then HIERARCHICAL binning: LDS histogram -> 8 global atomics per block
// (range reservation) -> conflict-free scatter. Kills the 8-address global
// atomic serialization that cost 751 us in round 1.
// ---------------------------------------------------------------------------
__global__ __launch_bounds__(256) void gate_topk_bin(
    const float* __restrict__ x, const float* __restrict__ gw,
    const float* __restrict__ gb,
    int* __restrict__ cnt, int* __restrict__ bidx, float* __restrict__ bp) {
    __shared__ int   se[2][256];
    __shared__ float sp[2][256];
    __shared__ int   hist[NE];
    __shared__ int   base[NE];

    const int tid  = threadIdx.x;
    const int lane = tid & 63, wid = tid >> 6;
    const int tok0 = blockIdx.x * 256;

    if (tid < NE) hist[tid] = 0;
    __syncthreads();

    // per-lane slice of gate weights: d-range [4*lane, 4*lane+4), all 8 experts
    const float* g0 = gw + lane * 32;
    float gwr[4][NE];
#pragma unroll
    for (int j = 0; j < 4; ++j)
#pragma unroll
        for (int e = 0; e < NE; ++e) gwr[j][e] = g0[j * 8 + e];

    for (int tt = 0; tt < 64; ++tt) {
        const int t = tok0 + wid * 64 + tt;
        float4 xv = *(const float4*)(x + (size_t)t * D + lane * 4);
        float xa[4] = {xv.x, xv.y, xv.z, xv.w};

        double acc[NE];
#pragma unroll
        for (int e = 0; e < NE; ++e) acc[e] = 0.0;
#pragma unroll
        for (int j = 0; j < 4; ++j)
#pragma unroll
            for (int e = 0; e < NE; ++e)
                acc[e] += (double)xa[j] * (double)gwr[j][e];

#pragma unroll
        for (int e = 0; e < NE; ++e) {
            double v = acc[e];
#pragma unroll
            for (int s = 1; s < 64; s <<= 1) v += __shfl_xor(v, s, 64);
            acc[e] = v;
        }

        if (lane == 0) {
            double l[NE];
#pragma unroll
            for (int e = 0; e < NE; ++e) l[e] = acc[e] + (double)gb[e];
            int e1 = 0;
#pragma unroll
            for (int e = 1; e < NE; ++e) if (l[e] > l[e1]) e1 = e;
            int e2 = (e1 == 0) ? 1 : 0;
#pragma unroll
            for (int e = 0; e < NE; ++e) if (e != e1 && l[e] > l[e2]) e2 = e;

            double s = 0.0;
#pragma unroll
            for (int e = 0; e < NE; ++e) s += exp(l[e] - l[e1]);
            const int slot = wid * 64 + tt;
            se[0][slot] = e1;
            se[1][slot] = e2;
            sp[0][slot] = (float)(1.0 / s);
            sp[1][slot] = (float)(exp(l[e2] - l[e1]) / s);
        }
    }
    __syncthreads();

    // LDS histogram: each thread owns one token, grabs local positions
    const int e1 = se[0][tid], e2 = se[1][tid];
    const int pos1 = atomicAdd(&hist[e1], 1);
    const int pos2 = atomicAdd(&hist[e2], 1);
    __syncthreads();

    // reserve global ranges: 8 atomics per block total
    if (tid < NE) base[tid] = atomicAdd(&cnt[tid], hist[tid]);
    __syncthreads();

    const int t = tok0 + tid;
    int o1 = e1 * N_TOK + base[e1] + pos1;
    int o2 = e2 * N_TOK + base[e2] + pos2;
    bidx[o1] = t;  bp[o1] = sp[0][tid];
    bidx[o2] = t;  bp[o2] = sp[1][tid];
}

// ---------------------------------------------------------------------------
// Expert FFN: fused relu(x@w1+b1)@w2+b2, 64-token x 256-out tile per block,
// DFF chunked by 32 (h stays in LDS). 4 waves; wave w owns token rows
// [16w,16w+16). MFMA 16x16x16 bf16 (_1k): A row=l&15,k=4*(l>>4)+j;
// D col=l&15,row=4*(l>>4)+reg.  blockIdx&7 = expert -> per-XCD L2 affinity.
// ---------------------------------------------------------------------------
__global__ __launch_bounds__(256) void expert_ffn(
    const float* __restrict__ x,
    const short* __restrict__ w1t_g,  // [E][DFF][D] bf16
    const short* __restrict__ w2t_g,  // [E][D][DFF] bf16
    const float* __restrict__ b1, const float* __restrict__ b2,
    const int* __restrict__ cnt, const int* __restrict__ bidx,
    const float* __restrict__ bp, float* __restrict__ out) {
    const int e    = blockIdx.x & 7;
    const int tile = blockIdx.x >> 3;
    const int n_e  = cnt[e];
    const int row0 = tile * 64;
    if (row0 >= n_e) return;

    __shared__ short xs[64][264];   // x tile, bf16   (33 KB)
    __shared__ short w1s[32][264];  // [f_local][d]   (17 KB)
    __shared__ short w2s[256][44];  // [d][f_local]   (22 KB)
    __shared__ short hs[64][44];    // [token][f_loc] ( 6 KB)
    __shared__ int   tok_s[64];
    __shared__ float p_s[64];

    const int tid  = threadIdx.x;
    const int lane = tid & 63, wid = tid >> 6;
    const int r16  = lane & 15, g = lane >> 4;

    if (tid < 64) {
        int r = row0 + tid;
        if (r < n_e) { tok_s[tid] = bidx[e * N_TOK + r]; p_s[tid] = bp[e * N_TOK + r]; }
        else         { tok_s[tid] = -1;                  p_s[tid] = 0.f; }
    }
    __syncthreads();

    // gather x rows -> xs (bf16); invalid rows zero-filled
#pragma unroll
    for (int rr = 0; rr < 64; rr += 4) {
        int r = rr + (tid >> 6);
        int c = (tid & 63) * 4;
        int tk = tok_s[r];
        float4 v = make_float4(0.f, 0.f, 0.f, 0.f);
        if (tk >= 0) v = *(const float4*)(x + (size_t)tk * D + c);
        xs[r][c + 0] = f2bf(v.x);
        xs[r][c + 1] = f2bf(v.y);
        xs[r][c + 2] = f2bf(v.z);
        xs[r][c + 3] = f2bf(v.w);
    }

    f32x4 acc[16];
#pragma unroll
    for (int i = 0; i < 16; ++i) acc[i] = (f32x4){0.f, 0.f, 0.f, 0.f};

    const size_t w1base = (size_t)e * DFF * D;
    const size_t w2base = (size_t)e * D * DFF;
    const int arow = wid * 16 + r16;

    for (int fc = 0; fc < DFF; fc += 32) {
        // stage w1 chunk: [fc..fc+32)[0..256) -> w1s[fl][d]  (contiguous copies)
        {
            int fl = tid >> 3;
            int c8 = (tid & 7) * 32;
            const short* sp = w1t_g + w1base + (size_t)(fc + fl) * D + c8;
            short* dp = &w1s[fl][c8];
#pragma unroll
            for (int i = 0; i < 4; ++i)
                *(int4*)(dp + i * 8) = *(const int4*)(sp + i * 8);
        }
        // stage w2 chunk: [d][fc..fc+32) -> w2s[d][fl]
        {
            const short* sp = w2t_g + w2base + (size_t)tid * DFF + fc;
            short* dp = &w2s[tid][0];
#pragma unroll
            for (int i = 0; i < 8; ++i)
                *(short4v*)(dp + i * 4) = *(const short4v*)(sp + i * 4);
        }
        __syncthreads();

        // GEMM1: h[64][32] = xs[64][256] @ w1chunk[256][32]
        f32x4 hacc[2] = {{0.f,0.f,0.f,0.f},{0.f,0.f,0.f,0.f}};
#pragma unroll
        for (int ks = 0; ks < 16; ++ks) {
            int k0 = ks * 16 + g * 4;
            short4v a = *(const short4v*)&xs[arow][k0];
#pragma unroll
            for (int c = 0; c < 2; ++c) {
                short4v b = *(const short4v*)&w1s[c * 16 + r16][k0];
                hacc[c] = __builtin_amdgcn_mfma_f32_16x16x16bf16_1k(a, b, hacc[c], 0, 0, 0);
            }
        }
        // bias + relu -> hs (bf16)
#pragma unroll
        for (int c = 0; c < 2; ++c) {
            float b1v = b1[e * DFF + fc + c * 16 + r16];
#pragma unroll
            for (int j = 0; j < 4; ++j) {
                float hv = hacc[c][j] + b1v;
                hv = fmaxf(hv, 0.f);
                hs[wid * 16 + g * 4 + j][c * 16 + r16] = f2bf(hv);
            }
        }
        __syncthreads();

        // GEMM2: out[64][256] += hs[64][32] @ w2chunk[32][256]
#pragma unroll
        for (int ks = 0; ks < 2; ++ks) {
            int k0 = ks * 16 + g * 4;
            short4v a = *(const short4v*)&hs[arow][k0];
#pragma unroll
            for (int nc = 0; nc < 16; ++nc) {
                short4v b = *(const short4v*)&w2s[nc * 16 + r16][k0];
                acc[nc] = __builtin_amdgcn_mfma_f32_16x16x16bf16_1k(a, b, acc[nc], 0, 0, 0);
            }
        }
        __syncthreads();  // protect w1s/w2s/hs before next chunk's staging
    }

    // epilogue: out[tok] += p * (acc + b2)   (exactly 2 atomic adds/element
    // from a zeroed buffer -> bitwise deterministic)
#pragma unroll
    for (int j = 0; j < 4; ++j) {
        int r = wid * 16 + g * 4 + j;
        int tk = tok_s[r];
        if (tk < 0) continue;
        float pv = p_s[r];
        float* orow = out + (size_t)tk * D;
#pragma unroll
        for (int nc = 0; nc < 16; ++nc) {
            int dcol = nc * 16 + r16;
            float v = (acc[nc][j] + b2[e * D + dcol]) * pv;
            atomicAdd(orow + dcol, v);
        }
    }
}

// ---------------------------------------------------------------------------
extern "C" void kernel_launch(void* const* d_in, const int* in_sizes, int n_in,
                              void* d_out, int out_size, void* d_ws, size_t ws_size,
                              hipStream_t stream) {
    const float* x  = (const float*)d_in[0];
    const float* gw = (const float*)d_in[1];
    const float* gb = (const float*)d_in[2];
    const float* w1 = (const float*)d_in[3];
    const float* b1 = (const float*)d_in[4];
    const float* w2 = (const float*)d_in[5];
    const float* b2 = (const float*)d_in[6];
    float* out = (float*)d_out;

    // ws layout: cnt[8] (pad 256B) | bidx 8*N int (1MB) | bp 8*N f32 (1MB)
    //          | w1t bf16 [E][DFF][D] (4MB) | w2t bf16 [E][D][DFF] (4MB)
    char* ws = (char*)d_ws;
    int*   cnt   = (int*)ws;
    int*   bidx  = (int*)(ws + 256);
    float* bp    = (float*)(ws + 256 + (size_t)NE * N_TOK * 4);
    short* w1t_g = (short*)(ws + 256 + (size_t)NE * N_TOK * 8);
    short* w2t_g = w1t_g + (size_t)NE * D * DFF;

    hipMemsetAsync(cnt, 0, 256, stream);
    hipMemsetAsync(d_out, 0, (size_t)out_size * sizeof(float), stream);

    transpose_to_bf16<<<NE * (D / 64) * (DFF / 64), 256, 0, stream>>>(w1, w1t_g, D, DFF);
    transpose_to_bf16<<<NE * (DFF / 64) * (D / 64), 256, 0, stream>>>(w2, w2t_g, DFF, D);
    gate_topk_bin<<<N_TOK / 256, 256, 0, stream>>>(x, gw, gb, cnt, bidx, bp);
    expert_ffn<<<NE * (N_TOK / 64), 256, 0, stream>>>(x, w1t_g, w2t_g, b1, b2,
                                                      cnt, bidx, bp, out);
}

// Round 3
// 194.559 us; speedup vs baseline: 5.8169x; 2.7621x over previous
//
#include <hip/hip_runtime.h>

#define N_TOK 32768
#define D 256
#define DFF 1024
#define NE 8

typedef __attribute__((ext_vector_type(4)))  float f32x4;
typedef __attribute__((ext_vector_type(16))) float f32x16;
typedef __attribute__((ext_vector_type(8)))  short bf16x8;

// fp32 -> bf16 round-to-nearest-even
__device__ __forceinline__ unsigned short f2bf(float f) {
    union { float f; unsigned u; } v; v.f = f;
    unsigned r = v.u + 0x7FFFu + ((v.u >> 16) & 1u);
    return (unsigned short)(r >> 16);
}

// ===========================================================================
// Prepass: w1 [E][D=256 d][DFF=1024 f] fp32  ->  frag-major bf16 for GEMM1-A.
// Frag grid per e: [fblk 0..32)[dblk 0..16); frag = 512 bf16 (1KB).
// Element (lane l, j): f = fblk*32 + (l&31), d = dblk*16 + (l>>5)*8 + j.
// Flat: w1f[frag*512 + l*8 + j], frag = (e*32+fblk)*16 + dblk.
// ===========================================================================
__global__ __launch_bounds__(256) void w1f_prep(
    const float* __restrict__ w1, short* __restrict__ w1f) {
    const int gid  = blockIdx.x * 256 + threadIdx.x;
    const int lane = gid & 63;
    const int frag = gid >> 6;
    const int dblk = frag & 15;
    const int fblk = (frag >> 4) & 31;
    const int e    = frag >> 9;
    const int l31 = lane & 31, g = lane >> 5;

    const float* src = w1 + ((size_t)e * 256 + dblk * 16 + g * 8) * 1024
                          + fblk * 32 + l31;
    unsigned u[4];
#pragma unroll
    for (int jp = 0; jp < 4; ++jp) {
        float a = src[(size_t)(jp * 2)     * 1024];
        float b = src[(size_t)(jp * 2 + 1) * 1024];
        u[jp] = (unsigned)f2bf(a) | ((unsigned)f2bf(b) << 16);
    }
    *(uint4*)(w1f + (size_t)gid * 8) = make_uint4(u[0], u[1], u[2], u[3]);
}

// ===========================================================================
// Prepass: w2 [E][DFF f][D col] fp32 -> frag-major bf16 for GEMM2-B.
// Frag grid per e: [cblk 0..8)[fblk 0..64).
// Element: col = cblk*32 + (l&31), f = fblk*16 + (l>>5)*8 + j.
// ===========================================================================
__global__ __launch_bounds__(256) void w2f_prep(
    const float* __restrict__ w2, short* __restrict__ w2f) {
    const int gid  = blockIdx.x * 256 + threadIdx.x;
    const int lane = gid & 63;
    const int frag = gid >> 6;
    const int fblk = frag & 63;
    const int cblk = (frag >> 6) & 7;
    const int e    = frag >> 9;
    const int l31 = lane & 31, g = lane >> 5;

    const float* src = w2 + ((size_t)e * 1024 + fblk * 16 + g * 8) * 256
                          + cblk * 32 + l31;
    unsigned u[4];
#pragma unroll
    for (int jp = 0; jp < 4; ++jp) {
        float a = src[(size_t)(jp * 2)     * 256];
        float b = src[(size_t)(jp * 2 + 1) * 256];
        u[jp] = (unsigned)f2bf(a) | ((unsigned)f2bf(b) << 16);
    }
    *(uint4*)(w2f + (size_t)gid * 8) = make_uint4(u[0], u[1], u[2], u[3]);
}

// ===========================================================================
// Gating v3: thread-per-token. fp64 accumulation (selection robustness vs np),
// gw broadcast from LDS, top-2 + fp64 softmax, hierarchical binning
// (LDS histogram -> 8 global atomics/block -> conflict-free scatter).
// ===========================================================================
__global__ __launch_bounds__(256) void gate_topk_bin(
    const float* __restrict__ x, const float* __restrict__ gw,
    const float* __restrict__ gb,
    int* __restrict__ cnt, int* __restrict__ bidx, float* __restrict__ bp) {
    __shared__ float gws[256 * 8];   // [d][e]
    __shared__ int   se1[256], se2[256];
    __shared__ float sp1[256], sp2[256];
    __shared__ int   hist[NE], base_[NE];

    const int tid = threadIdx.x;
#pragma unroll
    for (int i = 0; i < 8; ++i) gws[tid + 256 * i] = gw[tid + 256 * i];
    if (tid < NE) hist[tid] = 0;
    __syncthreads();

    const int t = blockIdx.x * 256 + tid;
    const float* xr = x + (size_t)t * D;

    double acc[NE];
#pragma unroll
    for (int e = 0; e < NE; ++e) acc[e] = 0.0;

    for (int d0 = 0; d0 < 256; d0 += 4) {
        float4 xv = *(const float4*)(xr + d0);
        float xa[4] = {xv.x, xv.y, xv.z, xv.w};
#pragma unroll
        for (int j = 0; j < 4; ++j) {
            const float* gr = &gws[(d0 + j) * 8];
            double xd = (double)xa[j];
#pragma unroll
            for (int e = 0; e < NE; ++e) acc[e] += xd * (double)gr[e];
        }
    }

    double l[NE];
#pragma unroll
    for (int e = 0; e < NE; ++e) l[e] = acc[e] + (double)gb[e];
    int e1 = 0;
#pragma unroll
    for (int e = 1; e < NE; ++e) if (l[e] > l[e1]) e1 = e;
    int e2 = (e1 == 0) ? 1 : 0;
#pragma unroll
    for (int e = 0; e < NE; ++e) if (e != e1 && l[e] > l[e2]) e2 = e;

    double s = 0.0;
#pragma unroll
    for (int e = 0; e < NE; ++e) s += exp(l[e] - l[e1]);
    se1[tid] = e1; se2[tid] = e2;
    sp1[tid] = (float)(1.0 / s);
    sp2[tid] = (float)(exp(l[e2] - l[e1]) / s);
    __syncthreads();

    const int pos1 = atomicAdd(&hist[se1[tid]], 1);
    const int pos2 = atomicAdd(&hist[se2[tid]], 1);
    __syncthreads();
    if (tid < NE) base_[tid] = atomicAdd(&cnt[tid], hist[tid]);
    __syncthreads();

    const int o1 = se1[tid] * N_TOK + base_[se1[tid]] + pos1;
    const int o2 = se2[tid] * N_TOK + base_[se2[tid]] + pos2;
    bidx[o1] = t;  bp[o1] = sp1[tid];
    bidx[o2] = t;  bp[o2] = sp2[tid];
}

// ===========================================================================
// Expert FFN v3. Block = 64 tokens x 256 out, 4 waves, fchunk = 128.
// MFMA 32x32x16 bf16. A/B frags read fragment-major (1KB contiguous per wave
// -> conflict/coalesce-optimal). Weights stream from L2 (frag-major global),
// x and h through LDS only. blockIdx&7 = expert -> per-XCD L2 affinity.
//   GEMM1 (h^T = w1 @ x^T): A = w1f frag [32f][16d], B = xs frag [16d][32tok].
//     D: col = tok (l&31), row = f_local (r&3)+8*(r>>2)+4*(l>>5). Wave wid
//     owns f-strip [wid*32, +32) of the 128-f chunk, all 64 tokens (2 frags).
//   GEMM2 (out += h @ w2): A = hs frag [32tok][16f], B = w2f [16f][32col].
//     Wave wid owns cols [wid*64, +64): acc 2(tok)x2(col) frags of 32x32.
// LDS: xs 32KB frag-major [dblk16][tok64][16] + hs 18KB [tok64][144]
// (stride 288B == 32 mod 128 -> uniform bank spread on b128 reads).
// ===========================================================================
__global__ __launch_bounds__(256, 2) void expert_ffn(
    const float* __restrict__ x,
    const short* __restrict__ w1f,
    const short* __restrict__ w2f,
    const float* __restrict__ b1, const float* __restrict__ b2,
    const int* __restrict__ cnt, const int* __restrict__ bidx,
    const float* __restrict__ bp, float* __restrict__ out) {
    const int e    = blockIdx.x & 7;
    const int tile = blockIdx.x >> 3;
    const int n_e  = cnt[e];
    const int row0 = tile * 64;
    if (row0 >= n_e) return;

    __shared__ short xs[16 * 64 * 16];   // [dblk][tok][16] 32KB
    __shared__ short hs[64 * 144];       // [tok][144]      18KB
    __shared__ int   tok_s[64];
    __shared__ float p_s[64];

    const int tid  = threadIdx.x;
    const int lane = tid & 63, wid = tid >> 6;
    const int l31  = lane & 31, g = lane >> 5;

    if (tid < 64) {
        int r = row0 + tid;
        if (r < n_e) { tok_s[tid] = bidx[e * N_TOK + r]; p_s[tid] = bp[e * N_TOK + r]; }
        else         { tok_s[tid] = -1;                  p_s[tid] = 0.f; }
    }
    __syncthreads();

    // ---- stage x tile -> xs (bf16, frag-major). thread: tok=tid>>2, 4 dblks.
    {
        const int tok = tid >> 2;
        const int tk  = tok_s[tok];
        const float* xrow = x + (size_t)(tk < 0 ? 0 : tk) * D;
#pragma unroll
        for (int i = 0; i < 4; ++i) {
            const int dblk = (tid & 3) * 4 + i;
            unsigned u[8];
            if (tk >= 0) {
#pragma unroll
                for (int q = 0; q < 4; ++q) {
                    float4 v = *(const float4*)(xrow + dblk * 16 + q * 4);
                    u[q * 2 + 0] = (unsigned)f2bf(v.x) | ((unsigned)f2bf(v.y) << 16);
                    u[q * 2 + 1] = (unsigned)f2bf(v.z) | ((unsigned)f2bf(v.w) << 16);
                }
            } else {
#pragma unroll
                for (int q = 0; q < 8; ++q) u[q] = 0;
            }
            short* dp = &xs[dblk * 1024 + tok * 16];
            *(uint4*)(dp)     = make_uint4(u[0], u[1], u[2], u[3]);
            *(uint4*)(dp + 8) = make_uint4(u[4], u[5], u[6], u[7]);
        }
    }

    f32x16 acc[2][2];   // [tok-half][col-half]
#pragma unroll
    for (int a = 0; a < 2; ++a)
#pragma unroll
        for (int b = 0; b < 2; ++b)
#pragma unroll
            for (int r = 0; r < 16; ++r) acc[a][b][r] = 0.f;

    const short* w1e = w1f + (size_t)e * 32 * 16 * 512;
    const short* w2e = w2f + (size_t)e * 8 * 64 * 512;
    const float* b1e = b1 + e * DFF;

    __syncthreads();

    for (int fc8 = 0; fc8 < 8; ++fc8) {
        // ---------- GEMM1: h^T[f 32-strip][tok 64] ----------
        f32x16 hacc[2];
#pragma unroll
        for (int c2 = 0; c2 < 2; ++c2)
#pragma unroll
            for (int r = 0; r < 16; ++r) hacc[c2][r] = 0.f;

        const short* w1p = w1e + ((size_t)(fc8 * 4 + wid) * 16) * 512 + lane * 8;
#pragma unroll
        for (int ks = 0; ks < 16; ++ks) {
            bf16x8 afr = *(const bf16x8*)(w1p + ks * 512);
            bf16x8 b0  = *(const bf16x8*)&xs[ks * 1024 + l31 * 16 + g * 8];
            bf16x8 b1f = *(const bf16x8*)&xs[ks * 1024 + (32 + l31) * 16 + g * 8];
            hacc[0] = __builtin_amdgcn_mfma_f32_32x32x16_bf16(afr, b0,  hacc[0], 0, 0, 0);
            hacc[1] = __builtin_amdgcn_mfma_f32_32x32x16_bf16(afr, b1f, hacc[1], 0, 0, 0);
        }

        // bias + relu + cvt -> hs[tok][128-f chunk]
        const float* b1p = b1e + fc8 * 128 + wid * 32;
#pragma unroll
        for (int c2 = 0; c2 < 2; ++c2) {
            const int tok = c2 * 32 + l31;
#pragma unroll
            for (int rp = 0; rp < 8; ++rp) {
                const int r0 = rp * 2;
                const int fl = (r0 & 3) + 8 * (r0 >> 2) + 4 * g;
                float v0 = fmaxf(hacc[c2][r0]     + b1p[fl],     0.f);
                float v1 = fmaxf(hacc[c2][r0 + 1] + b1p[fl + 1], 0.f);
                unsigned pk = (unsigned)f2bf(v0) | ((unsigned)f2bf(v1) << 16);
                *(unsigned*)&hs[tok * 144 + wid * 32 + fl] = pk;
            }
        }
        __syncthreads();

        // ---------- GEMM2: out[tok 64][col 64-strip] += h @ w2 ----------
        const short* w2p = w2e + (((size_t)(wid * 2) * 64) + fc8 * 8) * 512 + lane * 8;
#pragma unroll
        for (int ks2 = 0; ks2 < 8; ++ks2) {
            bf16x8 a0 = *(const bf16x8*)&hs[l31 * 144        + ks2 * 16 + g * 8];
            bf16x8 a1 = *(const bf16x8*)&hs[(32 + l31) * 144 + ks2 * 16 + g * 8];
            bf16x8 bb0 = *(const bf16x8*)(w2p + ks2 * 512);
            bf16x8 bb1 = *(const bf16x8*)(w2p + ks2 * 512 + 64 * 512);
            acc[0][0] = __builtin_amdgcn_mfma_f32_32x32x16_bf16(a0, bb0, acc[0][0], 0, 0, 0);
            acc[1][0] = __builtin_amdgcn_mfma_f32_32x32x16_bf16(a1, bb0, acc[1][0], 0, 0, 0);
            acc[0][1] = __builtin_amdgcn_mfma_f32_32x32x16_bf16(a0, bb1, acc[0][1], 0, 0, 0);
            acc[1][1] = __builtin_amdgcn_mfma_f32_32x32x16_bf16(a1, bb1, acc[1][1], 0, 0, 0);
        }
        __syncthreads();   // hs reused next fchunk
    }

    // ---- epilogue: out[tok] += p * (acc + b2). 2 commutative f32 atomic
    // adds per output element from a zeroed buffer -> deterministic.
    const float* b2e = b2 + e * D;
#pragma unroll
    for (int tb = 0; tb < 2; ++tb) {
#pragma unroll
        for (int cb = 0; cb < 2; ++cb) {
            const int col = wid * 64 + cb * 32 + l31;
            const float bv = b2e[col];
#pragma unroll
            for (int r = 0; r < 16; ++r) {
                const int tloc = tb * 32 + (r & 3) + 8 * (r >> 2) + 4 * g;
                const int tk = tok_s[tloc];
                if (tk >= 0)
                    atomicAdd(out + (size_t)tk * D + col,
                              (acc[tb][cb][r] + bv) * p_s[tloc]);
            }
        }
    }
}

// ---------------------------------------------------------------------------
extern "C" void kernel_launch(void* const* d_in, const int* in_sizes, int n_in,
                              void* d_out, int out_size, void* d_ws, size_t ws_size,
                              hipStream_t stream) {
    const float* x  = (const float*)d_in[0];
    const float* gw = (const float*)d_in[1];
    const float* gb = (const float*)d_in[2];
    const float* w1 = (const float*)d_in[3];
    const float* b1 = (const float*)d_in[4];
    const float* w2 = (const float*)d_in[5];
    const float* b2 = (const float*)d_in[6];
    float* out = (float*)d_out;

    // ws: cnt 256B | bidx 1MB | bp 1MB | w1f 4MB | w2f 4MB
    char* ws = (char*)d_ws;
    int*   cnt   = (int*)ws;
    int*   bidx  = (int*)(ws + 256);
    float* bp    = (float*)(ws + 256 + (size_t)NE * N_TOK * 4);
    short* w1f   = (short*)(ws + 256 + (size_t)NE * N_TOK * 8);
    short* w2f   = w1f + (size_t)NE * D * DFF;

    hipMemsetAsync(cnt, 0, 256, stream);
    hipMemsetAsync(d_out, 0, (size_t)out_size * sizeof(float), stream);

    w1f_prep<<<1024, 256, 0, stream>>>(w1, w1f);
    w2f_prep<<<1024, 256, 0, stream>>>(w2, w2f);
    gate_topk_bin<<<N_TOK / 256, 256, 0, stream>>>(x, gw, gb, cnt, bidx, bp);
    expert_ffn<<<NE * (N_TOK / 64), 256, 0, stream>>>(x, w1f, w2f, b1, b2,
                                                      cnt, bidx, bp, out);
}